// Round 6
// baseline (1319.815 us; speedup 1.0000x reference)
//
#include <hip/hip_runtime.h>

#define NNODES 200000
#define NEDGES 400000
#define FIN    165
#define K1P    192      // FIN padded to 6 x 32
#define HID    512
#define NB     ((NNODES + 255) / 256)   // 782 scan blocks

typedef __bf16 bf16_t;
typedef __bf16 bf16x8 __attribute__((ext_vector_type(8)));
typedef float  f32x4  __attribute__((ext_vector_type(4)));
typedef unsigned short su16x8 __attribute__((ext_vector_type(8)));
typedef float f32x4u __attribute__((ext_vector_type(4), aligned(4)));

static __device__ __forceinline__ float bf2f(unsigned short u) {
    unsigned int x = ((unsigned int)u) << 16;
    return __builtin_bit_cast(float, x);
}
static __device__ __forceinline__ unsigned short f2bf(float f) {
    bf16_t h = (bf16_t)f;  // RNE
    return __builtin_bit_cast(unsigned short, h);
}
// async global->LDS, 16B per lane (dest = wave-uniform base + lane*16)
static __device__ __forceinline__ void gl_lds16(const void* g, void* l) {
    __builtin_amdgcn_global_load_lds(
        (const __attribute__((address_space(1))) unsigned int*)g,
        (__attribute__((address_space(3))) unsigned int*)l, 16, 0, 0);
}

// ---------------- degree histograms ----------------
__global__ void k_deg(const int* __restrict__ src, const int* __restrict__ dst,
                      int* __restrict__ deg, int* __restrict__ cnt, int E) {
    int e = blockIdx.x * 256 + threadIdx.x;
    if (e < E) {
        atomicAdd(&deg[src[e]], 1);
        atomicAdd(&cnt[dst[e]], 1);
    }
}

// ---------------- CSR build: 2-level exclusive scan ----------------
__global__ void k_scan1(int* __restrict__ cnt, int* __restrict__ btot, int n) {
    __shared__ int s[256];
    int i = blockIdx.x * 256 + threadIdx.x;
    int v = (i < n) ? cnt[i] : 0;
    s[threadIdx.x] = v;
    __syncthreads();
    #pragma unroll
    for (int off = 1; off < 256; off <<= 1) {
        int t = (threadIdx.x >= off) ? s[threadIdx.x - off] : 0;
        __syncthreads();
        s[threadIdx.x] += t;
        __syncthreads();
    }
    if (i < n) cnt[i] = s[threadIdx.x] - v;
    if (threadIdx.x == 255) btot[blockIdx.x] = s[255];
}

__global__ void k_scan2(int* __restrict__ btot, int nb) {
    __shared__ int s[1024];
    int i = threadIdx.x;
    int v = (i < nb) ? btot[i] : 0;
    s[i] = v;
    __syncthreads();
    #pragma unroll
    for (int off = 1; off < 1024; off <<= 1) {
        int t = (i >= off) ? s[i - off] : 0;
        __syncthreads();
        s[i] += t;
        __syncthreads();
    }
    if (i < nb) btot[i] = s[i] - v;
}

__global__ void k_scan3(int* __restrict__ cnt, const int* __restrict__ btot,
                        int* __restrict__ rowptr, int n, int E) {
    int i = blockIdx.x * 256 + threadIdx.x;
    if (i < n) {
        rowptr[i] = cnt[i] + btot[blockIdx.x];
        cnt[i] = 0;
    }
    if (i == 0) rowptr[n] = E;
}

__global__ void k_scatter(const int* __restrict__ src, const int* __restrict__ dst,
                          const int* __restrict__ rowptr, int* __restrict__ cur,
                          int* __restrict__ esrc, int E) {
    int e = blockIdx.x * 256 + threadIdx.x;
    if (e < E) {
        int d = dst[e];
        int pos = rowptr[d] + atomicAdd(&cur[d], 1);
        esrc[pos] = src[e];
    }
}

// ---------------- build transposed bf16 B panels ----------------
__global__ void k_buildB1(const float* __restrict__ W1_0, const float* __restrict__ W1_1,
                          unsigned short* __restrict__ Bct1) {
    int idx = blockIdx.x * 256 + threadIdx.x;   // 1024 * K1P
    if (idx >= 1024 * K1P) return;
    int n = idx / K1P, k = idx % K1P;
    float v = 0.f;
    if (k < FIN) v = (n < HID) ? W1_0[k * HID + n] : W1_1[k * HID + (n - HID)];
    Bct1[idx] = f2bf(v);
}

__global__ void k_buildB2(const float* __restrict__ W2_0, const float* __restrict__ W2_1,
                          unsigned short* __restrict__ Bct2) {
    int idx = blockIdx.x * 256 + threadIdx.x;   // 1024 * 512
    if (idx >= 1024 * HID) return;
    int n = idx >> 9, k = idx & 511;
    float v = (n < HID) ? W2_0[k * HID + n] : W2_1[k * HID + (n - HID)];
    Bct2[idx] = f2bf(v);
}

// ---------------- x -> bf16 padded [NNODES x 192] ----------------
__global__ void k_xcvt(const float* __restrict__ x, unsigned short* __restrict__ xb) {
    long i = ((long)blockIdx.x * 256 + threadIdx.x) * 8;
    if (i >= (long)NNODES * K1P) return;
    int row = (int)(i / K1P), k = (int)(i % K1P);
    const float* xr = x + (size_t)row * FIN;
    __align__(16) unsigned short v[8];
    #pragma unroll
    for (int j = 0; j < 8; ++j)
        v[j] = (k + j < FIN) ? f2bf(xr[k + j]) : (unsigned short)0;
    *(su16x8*)&xb[i] = *(su16x8*)v;
}

// ---------------- gload_lds GEMM: U[:, ooff..+512) = A @ Bct (bf16 A) ----------------
// 2-phase dbuf, swapped-operand MFMA -> lane holds 4 consecutive cols -> 8B stores.
// In-place safe (block reads only its own 128 rows; reads precede epilogue stores).
template<int K, int LDA>
__global__ __launch_bounds__(512, 1)
void k_gemmt(const unsigned short* __restrict__ A, const unsigned short* __restrict__ Bct,
             unsigned short* __restrict__ U, int ooff, int M) {
    constexpr int KT = K / 32;
    __shared__ unsigned short Al[2][128 * 32];    // 16 KB
    __shared__ unsigned short Bl[2][4][HID * 8];  // 64 KB

    const int t    = threadIdx.x;
    const int lane = t & 63;
    const int wv   = t >> 6;
    const int wm   = wv >> 2, wn = wv & 3;
    const int m0   = blockIdx.x * 128;

    const int srow = t >> 2;
    const int gch  = ((t & 3) ^ ((srow >> 1) & 3)) * 8;  // inverse source swizzle
    const unsigned short* Ab = A + (size_t)(m0 + srow) * LDA + gch;
    const bool rok = (m0 + srow) < M;   // wave-uniform (M % 16 == 0)
    const unsigned short* Bb = Bct + (size_t)t * K;

    f32x4 acc[4][8];
    #pragma unroll
    for (int m = 0; m < 4; ++m)
        #pragma unroll
        for (int n = 0; n < 8; ++n)
            acc[m][n] = (f32x4){0.f, 0.f, 0.f, 0.f};

    if (rok) gl_lds16(Ab, &Al[0][t * 8]);
    #pragma unroll
    for (int q = 0; q < 4; ++q) gl_lds16(Bb + q * 8, &Bl[0][q][t * 8]);
    __syncthreads();

    int cur = 0;
    for (int kt = 0; kt < KT; ++kt) {
        if (kt + 1 < KT) {
            const int k0 = (kt + 1) * 32;
            if (rok) gl_lds16(Ab + k0, &Al[cur ^ 1][t * 8]);
            #pragma unroll
            for (int q = 0; q < 4; ++q)
                gl_lds16(Bb + k0 + q * 8, &Bl[cur ^ 1][q][t * 8]);
        }
        bf16x8 af[4], bfr[8];
        #pragma unroll
        for (int m = 0; m < 4; ++m) {
            int r  = wm * 64 + m * 16 + (lane & 15);
            int kq = lane >> 4;
            af[m] = *(const bf16x8*)&Al[cur][r * 32 + 8 * (kq ^ ((r >> 1) & 3))];
        }
        #pragma unroll
        for (int n = 0; n < 8; ++n) {
            int c = wn * 128 + n * 16 + (lane & 15);
            bfr[n] = *(const bf16x8*)&Bl[cur][lane >> 4][c * 8];
        }
        // swapped operands: D = (A@B)^T in registers
        #pragma unroll
        for (int m = 0; m < 4; ++m)
            #pragma unroll
            for (int n = 0; n < 8; ++n)
                acc[m][n] = __builtin_amdgcn_mfma_f32_16x16x32_bf16(bfr[n], af[m], acc[m][n], 0, 0, 0);
        __syncthreads();
        cur ^= 1;
    }

    // epilogue: lane holds C[r = ..+(lane&15)][c..c+3] -> one 8B store per (m,n)
    #pragma unroll
    for (int m = 0; m < 4; ++m) {
        int r = m0 + wm * 64 + m * 16 + (lane & 15);
        if (r < M) {
            #pragma unroll
            for (int n = 0; n < 8; ++n) {
                int cb = ooff + wn * 128 + n * 16 + (lane >> 4) * 4;
                uint2 pk;
                pk.x = ((unsigned int)f2bf(acc[m][n][1]) << 16) | (unsigned int)f2bf(acc[m][n][0]);
                pk.y = ((unsigned int)f2bf(acc[m][n][3]) << 16) | (unsigned int)f2bf(acc[m][n][2]);
                *(uint2*)&U[(size_t)r * 1024 + cb] = pk;
            }
        }
    }
}

// ---------------- fallback GEMM0 (f32 A, reg-staged; round-5 proven + new epilogue) ------
__global__ __launch_bounds__(512, 1)
void k_gemm0(const float* __restrict__ Aptr, const unsigned short* __restrict__ Bct,
             unsigned short* __restrict__ U, int M) {
    constexpr int K  = K1P;
    constexpr int KT = K / 32;
    __shared__ unsigned short Al[128 * 32];
    __shared__ unsigned short Bpl[4][HID * 8];

    const int t    = threadIdx.x;
    const int lane = t & 63;
    const int wv   = t >> 6;
    const int wm   = wv >> 2, wn = wv & 3;
    const int m0   = blockIdx.y * 128;
    const int n0   = blockIdx.x * 512;

    f32x4 acc[4][8];
    #pragma unroll
    for (int m = 0; m < 4; ++m)
        #pragma unroll
        for (int n = 0; n < 8; ++n)
            acc[m][n] = (f32x4){0.f, 0.f, 0.f, 0.f};

    const int srow = t >> 2, sch = t & 3;
    const bool rok = (m0 + srow) < M;

    for (int kt = 0; kt < KT; ++kt) {
        const int k0 = kt * 32;
        __syncthreads();
        {
            const int gk = k0 + sch * 8;
            su16x8 av;
            float f[8];
            const float* Ab = Aptr + (size_t)(m0 + srow) * FIN + gk;
            if (rok && gk + 8 <= FIN) {
                f32x4u lo = *(const f32x4u*)Ab;
                f32x4u hi = *(const f32x4u*)(Ab + 4);
                f[0]=lo.x; f[1]=lo.y; f[2]=lo.z; f[3]=lo.w;
                f[4]=hi.x; f[5]=hi.y; f[6]=hi.z; f[7]=hi.w;
            } else {
                #pragma unroll
                for (int j = 0; j < 8; ++j)
                    f[j] = (rok && gk + j < FIN) ? Ab[j] : 0.f;
            }
            #pragma unroll
            for (int j = 0; j < 8; ++j) av[j] = f2bf(f[j]);
            *(su16x8*)&Al[srow * 32 + 8 * (sch ^ ((srow >> 1) & 3))] = av;
        }
        {
            const unsigned short* Bb = Bct + (size_t)(n0 + t) * K + k0;
            #pragma unroll
            for (int q = 0; q < 4; ++q)
                *(su16x8*)&Bpl[q][t * 8] = *(const su16x8*)(Bb + q * 8);
        }
        __syncthreads();
        bf16x8 af[4], bfr[8];
        #pragma unroll
        for (int m = 0; m < 4; ++m) {
            int r  = wm * 64 + m * 16 + (lane & 15);
            int kq = lane >> 4;
            af[m] = *(const bf16x8*)&Al[r * 32 + 8 * (kq ^ ((r >> 1) & 3))];
        }
        #pragma unroll
        for (int n = 0; n < 8; ++n) {
            int c = wn * 128 + n * 16 + (lane & 15);
            bfr[n] = *(const bf16x8*)&Bpl[lane >> 4][c * 8];
        }
        #pragma unroll
        for (int m = 0; m < 4; ++m)
            #pragma unroll
            for (int n = 0; n < 8; ++n)
                acc[m][n] = __builtin_amdgcn_mfma_f32_16x16x32_bf16(bfr[n], af[m], acc[m][n], 0, 0, 0);
    }

    #pragma unroll
    for (int m = 0; m < 4; ++m) {
        int r = m0 + wm * 64 + m * 16 + (lane & 15);
        if (r < M) {
            #pragma unroll
            for (int n = 0; n < 8; ++n) {
                int cb = n0 + wn * 128 + n * 16 + (lane >> 4) * 4;
                uint2 pk;
                pk.x = ((unsigned int)f2bf(acc[m][n][1]) << 16) | (unsigned int)f2bf(acc[m][n][0]);
                pk.y = ((unsigned int)f2bf(acc[m][n][3]) << 16) | (unsigned int)f2bf(acc[m][n][2]);
                *(uint2*)&U[(size_t)r * 1024 + cb] = pk;
            }
        }
    }
}

// ---------------- aggr: U0[d] += sum_e w_e * U1[src_e]; optional fused bias+relu -------
template<int RELU>
__global__ void k_aggr(unsigned short* U, const int* __restrict__ rowptr,
                       const int* __restrict__ esrc, const int* __restrict__ deg,
                       const float* __restrict__ bias, int M) {
    int wid  = (blockIdx.x * 256 + threadIdx.x) >> 6;
    int lane = threadIdx.x & 63;
    if (wid >= M) return;
    int e0 = rowptr[wid], e1 = rowptr[wid + 1];
    if (RELU == 0 && e0 == e1) return;

    unsigned short* u0 = U + (size_t)wid * 1024 + lane * 8;
    uint4 v0 = *(const uint4*)u0;
    unsigned int a0[4] = {v0.x, v0.y, v0.z, v0.w};
    float acc[8];
    #pragma unroll
    for (int i = 0; i < 4; ++i) {
        acc[2 * i]     = bf2f((unsigned short)(a0[i] & 0xffffu));
        acc[2 * i + 1] = bf2f((unsigned short)(a0[i] >> 16));
    }

    if (e0 < e1) {
        int dd = deg[wid];
        float dr = dd > 0 ? rsqrtf((float)dd) : 0.f;
        for (int e = e0; e < e1; ++e) {
            int s = esrc[e];
            float we = -dr * rsqrtf((float)deg[s]);
            const uint4 v = *(const uint4*)(U + (size_t)s * 1024 + 512 + lane * 8);
            unsigned int uu[4] = {v.x, v.y, v.z, v.w};
            #pragma unroll
            for (int i = 0; i < 4; ++i) {
                acc[2 * i]     += we * bf2f((unsigned short)(uu[i] & 0xffffu));
                acc[2 * i + 1] += we * bf2f((unsigned short)(uu[i] >> 16));
            }
        }
    }

    if (RELU) {
        float4 c0 = *(const float4*)(bias + lane * 8);
        float4 c1 = *(const float4*)(bias + lane * 8 + 4);
        float bb[8] = {c0.x,c0.y,c0.z,c0.w,c1.x,c1.y,c1.z,c1.w};
        #pragma unroll
        for (int i = 0; i < 8; ++i) {
            float f = acc[i] + bb[i];
            acc[i] = f > 0.f ? f : 0.f;
        }
    }
    uint4 w4;
    unsigned int* wo = (unsigned int*)&w4;
    #pragma unroll
    for (int i = 0; i < 4; ++i)
        wo[i] = ((unsigned int)f2bf(acc[2 * i + 1]) << 16) | (unsigned int)f2bf(acc[2 * i]);
    *(uint4*)u0 = w4;
}

// ---------------- fused aggr + final: out[d] = relu(U0[d]+prop+b2) @ Wl + bl ----------
__global__ void k_aggrf(const unsigned short* __restrict__ U, const int* __restrict__ rowptr,
                        const int* __restrict__ esrc, const int* __restrict__ deg,
                        const float* __restrict__ b2, const float* __restrict__ Wl,
                        const float* __restrict__ bl, float* __restrict__ out, int M) {
    int wid  = (blockIdx.x * 256 + threadIdx.x) >> 6;
    int lane = threadIdx.x & 63;
    if (wid >= M) return;
    int e0 = rowptr[wid], e1 = rowptr[wid + 1];

    const uint4 v0 = *(const uint4*)(U + (size_t)wid * 1024 + lane * 8);
    unsigned int a0[4] = {v0.x, v0.y, v0.z, v0.w};
    float acc[8];
    #pragma unroll
    for (int i = 0; i < 4; ++i) {
        acc[2 * i]     = bf2f((unsigned short)(a0[i] & 0xffffu));
        acc[2 * i + 1] = bf2f((unsigned short)(a0[i] >> 16));
    }
    if (e0 < e1) {
        int dd = deg[wid];
        float dr = dd > 0 ? rsqrtf((float)dd) : 0.f;
        for (int e = e0; e < e1; ++e) {
            int s = esrc[e];
            float we = -dr * rsqrtf((float)deg[s]);
            const uint4 v = *(const uint4*)(U + (size_t)s * 1024 + 512 + lane * 8);
            unsigned int uu[4] = {v.x, v.y, v.z, v.w};
            #pragma unroll
            for (int i = 0; i < 4; ++i) {
                acc[2 * i]     += we * bf2f((unsigned short)(uu[i] & 0xffffu));
                acc[2 * i + 1] += we * bf2f((unsigned short)(uu[i] >> 16));
            }
        }
    }
    float4 c0 = *(const float4*)(b2 + lane * 8);
    float4 c1 = *(const float4*)(b2 + lane * 8 + 4);
    float bb[8] = {c0.x,c0.y,c0.z,c0.w,c1.x,c1.y,c1.z,c1.w};
    const float4* Wp = reinterpret_cast<const float4*>(Wl + lane * 16);
    float4 w0 = Wp[0], w1 = Wp[1], w2 = Wp[2], w3 = Wp[3];
    float wv[16] = {w0.x, w0.y, w0.z, w0.w, w1.x, w1.y, w1.z, w1.w,
                    w2.x, w2.y, w2.z, w2.w, w3.x, w3.y, w3.z, w3.w};
    float s0 = 0.f, s1 = 0.f;
    #pragma unroll
    for (int i = 0; i < 8; ++i) {
        float f = acc[i] + bb[i];
        f = f > 0.f ? f : 0.f;
        s0 += f * wv[2 * i];
        s1 += f * wv[2 * i + 1];
    }
    #pragma unroll
    for (int off = 32; off; off >>= 1) {
        s0 += __shfl_xor(s0, off, 64);
        s1 += __shfl_xor(s1, off, 64);
    }
    if (lane == 0) {
        out[2 * (size_t)wid]     = s0 + bl[0];
        out[2 * (size_t)wid + 1] = s1 + bl[1];
    }
}

// ---------------- fallback final (when esrc lives in d_out) ----------------
__global__ void k_final(const unsigned short* __restrict__ U, const float* __restrict__ b2,
                        const float* __restrict__ Wl, const float* __restrict__ bl,
                        float* __restrict__ out, int M) {
    int wid  = (blockIdx.x * 256 + threadIdx.x) >> 6;
    int lane = threadIdx.x & 63;
    if (wid >= M) return;
    const uint4 v = *(const uint4*)(U + (size_t)wid * 1024 + lane * 8);
    float4 c0 = *(const float4*)(b2 + lane * 8);
    float4 c1 = *(const float4*)(b2 + lane * 8 + 4);
    float bb[8] = {c0.x,c0.y,c0.z,c0.w,c1.x,c1.y,c1.z,c1.w};
    const float4* Wp = reinterpret_cast<const float4*>(Wl + lane * 16);
    float4 w0 = Wp[0], w1 = Wp[1], w2 = Wp[2], w3 = Wp[3];
    float wv[16] = {w0.x, w0.y, w0.z, w0.w, w1.x, w1.y, w1.z, w1.w,
                    w2.x, w2.y, w2.z, w2.w, w3.x, w3.y, w3.z, w3.w};
    unsigned int uu[4] = {v.x, v.y, v.z, v.w};
    float s0 = 0.f, s1 = 0.f;
    #pragma unroll
    for (int j = 0; j < 4; ++j) {
        float f0 = bf2f((unsigned short)(uu[j] & 0xffffu)) + bb[2 * j];
        float f1 = bf2f((unsigned short)(uu[j] >> 16))     + bb[2 * j + 1];
        f0 = f0 > 0.f ? f0 : 0.f;
        f1 = f1 > 0.f ? f1 : 0.f;
        s0 += f0 * wv[4 * j + 0];
        s1 += f0 * wv[4 * j + 1];
        s0 += f1 * wv[4 * j + 2];
        s1 += f1 * wv[4 * j + 3];
    }
    #pragma unroll
    for (int off = 32; off; off >>= 1) {
        s0 += __shfl_xor(s0, off, 64);
        s1 += __shfl_xor(s1, off, 64);
    }
    if (lane == 0) {
        out[2 * (size_t)wid]     = s0 + bl[0];
        out[2 * (size_t)wid + 1] = s1 + bl[1];
    }
}

extern "C" void kernel_launch(void* const* d_in, const int* in_sizes, int n_in,
                              void* d_out, int out_size, void* d_ws, size_t ws_size,
                              hipStream_t stream) {
    const float* x    = (const float*)d_in[0];
    const int*   ei   = (const int*)d_in[1];
    const float* W1_0 = (const float*)d_in[2];
    const float* W1_1 = (const float*)d_in[3];
    const float* b1   = (const float*)d_in[4];
    const float* W2_0 = (const float*)d_in[5];
    const float* W2_1 = (const float*)d_in[6];
    const float* b2   = (const float*)d_in[7];
    const float* Wl   = (const float*)d_in[8];
    const float* bl   = (const float*)d_in[9];
    const int* src = ei;
    const int* dst = ei + NEDGES;
    float* out = (float*)d_out;

    char* ws = (char*)d_ws;
    size_t off = 0;
    auto alloc = [&](size_t bytes) -> void* {
        void* p = ws + off;
        off += (bytes + 255) & ~(size_t)255;
        return p;
    };
    int*            deg    = (int*)alloc((size_t)NNODES * 4);
    int*            cnt    = (int*)alloc((size_t)NNODES * 4);
    int*            rowptr = (int*)alloc((size_t)(NNODES + 1) * 4);
    int*            btot   = (int*)alloc((size_t)NB * 4);
    unsigned short* Bct1   = (unsigned short*)alloc((size_t)1024 * K1P * 2);
    unsigned short* Bct2   = (unsigned short*)alloc((size_t)1024 * HID * 2);
    unsigned short* U      = (unsigned short*)alloc((size_t)NNODES * 1024 * 2);

    // esrc: prefer ws (enables fused aggr+final); else d_out (then final must be separate)
    bool esrc_ws = (off + (size_t)NEDGES * 4 <= ws_size);
    int* esrc = esrc_ws ? (int*)alloc((size_t)NEDGES * 4) : (int*)d_out;
    // xb: bf16-converted x (enables gload_lds layer-1 GEMM); fallback to f32 path
    bool have_xb = (off + (size_t)NNODES * K1P * 2 <= ws_size);
    unsigned short* xb = have_xb ? (unsigned short*)alloc((size_t)NNODES * K1P * 2) : nullptr;

    hipMemsetAsync(deg, 0, (size_t)NNODES * 4, stream);
    hipMemsetAsync(cnt, 0, (size_t)NNODES * 4, stream);

    // CSR build + degrees
    k_deg    <<<(NEDGES + 255) / 256, 256, 0, stream>>>(src, dst, deg, cnt, NEDGES);
    k_scan1  <<<NB, 256, 0, stream>>>(cnt, btot, NNODES);
    k_scan2  <<<1, 1024, 0, stream>>>(btot, NB);
    k_scan3  <<<NB, 256, 0, stream>>>(cnt, btot, rowptr, NNODES, NEDGES);
    k_scatter<<<(NEDGES + 255) / 256, 256, 0, stream>>>(src, dst, rowptr, cnt, esrc, NEDGES);

    k_buildB1<<<(1024 * K1P + 255) / 256, 256, 0, stream>>>(W1_0, W1_1, Bct1);
    k_buildB2<<<(1024 * HID + 255) / 256, 256, 0, stream>>>(W2_0, W2_1, Bct2);

    const int nblk = (NNODES + 127) / 128;

    // layer 1: U = x @ [W1_0|W1_1]
    if (have_xb) {
        k_xcvt<<<(int)(((long)NNODES * K1P / 8 + 255) / 256), 256, 0, stream>>>(x, xb);
        k_gemmt<K1P, K1P><<<nblk, 512, 0, stream>>>(xb, Bct1, U, 0, NNODES);
        k_gemmt<K1P, K1P><<<nblk, 512, 0, stream>>>(xb, Bct1 + (size_t)HID * K1P, U, 512, NNODES);
    } else {
        k_gemm0<<<dim3(2, nblk), 512, 0, stream>>>(x, Bct1, U, NNODES);
    }
    // aggr folds prop + bias + relu -> U0 = h1
    k_aggr<1><<<NNODES / 4, 256, 0, stream>>>(U, rowptr, esrc, deg, b1, NNODES);

    // layer 2: U1 <- h1@W2_1 first, then U0 <- h1@W2_0 (in-place)
    k_gemmt<HID, 1024><<<nblk, 512, 0, stream>>>(U, Bct2 + (size_t)HID * HID, U, 512, NNODES);
    k_gemmt<HID, 1024><<<nblk, 512, 0, stream>>>(U, Bct2, U, 0, NNODES);

    // prop + bias + relu + final GEMV
    if (esrc_ws) {
        k_aggrf<<<NNODES / 4, 256, 0, stream>>>(U, rowptr, esrc, deg, b2, Wl, bl, out, NNODES);
    } else {
        k_aggr<0><<<NNODES / 4, 256, 0, stream>>>(U, rowptr, esrc, deg, nullptr, NNODES);
        k_final<<<NNODES / 4, 256, 0, stream>>>(U, b2, Wl, bl, out, NNODES);
    }
}

// Round 7
// 1094.034 us; speedup vs baseline: 1.2064x; 1.2064x over previous
//
#include <hip/hip_runtime.h>

#define NNODES 200000
#define NEDGES 400000
#define FIN    165
#define K1P    192      // FIN padded to 6 x 32
#define HID    512
#define NB     ((NNODES + 255) / 256)   // 782 scan blocks

typedef __bf16 bf16_t;
typedef __bf16 bf16x8 __attribute__((ext_vector_type(8)));
typedef float  f32x4  __attribute__((ext_vector_type(4)));
typedef unsigned short su16x8 __attribute__((ext_vector_type(8)));
typedef float f32x4u __attribute__((ext_vector_type(4), aligned(4)));

static __device__ __forceinline__ float bf2f(unsigned short u) {
    unsigned int x = ((unsigned int)u) << 16;
    return __builtin_bit_cast(float, x);
}
static __device__ __forceinline__ unsigned short f2bf(float f) {
    bf16_t h = (bf16_t)f;  // RNE
    return __builtin_bit_cast(unsigned short, h);
}
// async global->LDS, 16B per lane (dest = wave-uniform base + lane*16)
static __device__ __forceinline__ void gl_lds16(const void* g, void* l) {
    __builtin_amdgcn_global_load_lds(
        (const __attribute__((address_space(1))) unsigned int*)g,
        (__attribute__((address_space(3))) unsigned int*)l, 16, 0, 0);
}

// ---------------- degree histograms ----------------
__global__ void k_deg(const int* __restrict__ src, const int* __restrict__ dst,
                      int* __restrict__ deg, int* __restrict__ cnt, int E) {
    int e = blockIdx.x * 256 + threadIdx.x;
    if (e < E) {
        atomicAdd(&deg[src[e]], 1);
        atomicAdd(&cnt[dst[e]], 1);
    }
}

// ---------------- CSR build: 2-level exclusive scan ----------------
__global__ void k_scan1(int* __restrict__ cnt, int* __restrict__ btot, int n) {
    __shared__ int s[256];
    int i = blockIdx.x * 256 + threadIdx.x;
    int v = (i < n) ? cnt[i] : 0;
    s[threadIdx.x] = v;
    __syncthreads();
    #pragma unroll
    for (int off = 1; off < 256; off <<= 1) {
        int t = (threadIdx.x >= off) ? s[threadIdx.x - off] : 0;
        __syncthreads();
        s[threadIdx.x] += t;
        __syncthreads();
    }
    if (i < n) cnt[i] = s[threadIdx.x] - v;
    if (threadIdx.x == 255) btot[blockIdx.x] = s[255];
}

__global__ void k_scan2(int* __restrict__ btot, int nb) {
    __shared__ int s[1024];
    int i = threadIdx.x;
    int v = (i < nb) ? btot[i] : 0;
    s[i] = v;
    __syncthreads();
    #pragma unroll
    for (int off = 1; off < 1024; off <<= 1) {
        int t = (i >= off) ? s[i - off] : 0;
        __syncthreads();
        s[i] += t;
        __syncthreads();
    }
    if (i < nb) btot[i] = s[i] - v;
}

__global__ void k_scan3(int* __restrict__ cnt, const int* __restrict__ btot,
                        int* __restrict__ rowptr, int n, int E) {
    int i = blockIdx.x * 256 + threadIdx.x;
    if (i < n) {
        rowptr[i] = cnt[i] + btot[blockIdx.x];
        cnt[i] = 0;
    }
    if (i == 0) rowptr[n] = E;
}

__global__ void k_scatter(const int* __restrict__ src, const int* __restrict__ dst,
                          const int* __restrict__ rowptr, int* __restrict__ cur,
                          int* __restrict__ esrc, int E) {
    int e = blockIdx.x * 256 + threadIdx.x;
    if (e < E) {
        int d = dst[e];
        int pos = rowptr[d] + atomicAdd(&cur[d], 1);
        esrc[pos] = src[e];
    }
}

// ---------------- build k-tiled bf16 B panel: P[kt][q][n][j] = W[kt*32+q*8+j][n] -------
// Panel is the exact per-k-tile LDS image -> staging loads are fully contiguous.
__global__ void k_buildP(const float* __restrict__ W, unsigned short* __restrict__ P,
                         int kp, int kfull) {
    int idx = blockIdx.x * 256 + threadIdx.x;
    if (idx >= kp * HID) return;
    int j  = idx & 7;
    int n  = (idx >> 3) & 511;
    int q  = (idx >> 12) & 3;
    int kt = idx >> 14;
    int k  = kt * 32 + q * 8 + j;
    P[idx] = (k < kfull) ? f2bf(W[(size_t)k * HID + n]) : (unsigned short)0;
}

// ---------------- x -> bf16 padded [NNODES x 192] ----------------
__global__ void k_xcvt(const float* __restrict__ x, unsigned short* __restrict__ xb) {
    long i = ((long)blockIdx.x * 256 + threadIdx.x) * 8;
    if (i >= (long)NNODES * K1P) return;
    int row = (int)(i / K1P), k = (int)(i % K1P);
    const float* xr = x + (size_t)row * FIN;
    __align__(16) unsigned short v[8];
    #pragma unroll
    for (int j = 0; j < 8; ++j)
        v[j] = (k + j < FIN) ? f2bf(xr[k + j]) : (unsigned short)0;
    *(su16x8*)&xb[i] = *(su16x8*)v;
}

// ---------------- gload_lds GEMM: U[:, ooff..+512) = A @ P (bf16 A, k-tiled P) --------
// 2-phase dbuf; swapped-operand MFMA -> 8B stores. In-place safe (block reads only
// its own 128 rows; all reads precede the epilogue stores).
template<int K, int LDA>
__global__ __launch_bounds__(512, 1)
void k_gemmt(const unsigned short* __restrict__ A, const unsigned short* __restrict__ P,
             unsigned short* __restrict__ U, int ooff, int M) {
    constexpr int KT = K / 32;
    __shared__ unsigned short Al[2][128 * 32];    // 16 KB
    __shared__ unsigned short Bl[2][4][HID * 8];  // 64 KB

    const int t    = threadIdx.x;
    const int lane = t & 63;
    const int wv   = t >> 6;
    const int wm   = wv >> 2, wn = wv & 3;
    const int m0   = blockIdx.x * 128;

    const int srow = t >> 2;
    const int gch  = ((t & 3) ^ ((srow >> 1) & 3)) * 8;  // inverse source swizzle
    const unsigned short* Ab = A + (size_t)(m0 + srow) * LDA + gch;
    const bool rok = (m0 + srow) < M;
    const unsigned short* Pb = P + (size_t)t * 8;  // contiguous 1KB per wave-instr

    f32x4 acc[4][8];
    #pragma unroll
    for (int m = 0; m < 4; ++m)
        #pragma unroll
        for (int n = 0; n < 8; ++n)
            acc[m][n] = (f32x4){0.f, 0.f, 0.f, 0.f};

    if (rok) gl_lds16(Ab, &Al[0][t * 8]);
    #pragma unroll
    for (int q = 0; q < 4; ++q) gl_lds16(Pb + q * 4096, &Bl[0][q][t * 8]);
    __syncthreads();

    int cur = 0;
    for (int kt = 0; kt < KT; ++kt) {
        if (kt + 1 < KT) {
            if (rok) gl_lds16(Ab + (kt + 1) * 32, &Al[cur ^ 1][t * 8]);
            const unsigned short* Pn = Pb + (size_t)(kt + 1) * 16384;
            #pragma unroll
            for (int q = 0; q < 4; ++q)
                gl_lds16(Pn + q * 4096, &Bl[cur ^ 1][q][t * 8]);
        }
        bf16x8 af[4], bfr[8];
        #pragma unroll
        for (int m = 0; m < 4; ++m) {
            int r  = wm * 64 + m * 16 + (lane & 15);
            int kq = lane >> 4;
            af[m] = *(const bf16x8*)&Al[cur][r * 32 + 8 * (kq ^ ((r >> 1) & 3))];
        }
        #pragma unroll
        for (int n = 0; n < 8; ++n) {
            int c = wn * 128 + n * 16 + (lane & 15);
            bfr[n] = *(const bf16x8*)&Bl[cur][lane >> 4][c * 8];
        }
        // swapped operands: D = (A@B)^T in registers
        #pragma unroll
        for (int m = 0; m < 4; ++m)
            #pragma unroll
            for (int n = 0; n < 8; ++n)
                acc[m][n] = __builtin_amdgcn_mfma_f32_16x16x32_bf16(bfr[n], af[m], acc[m][n], 0, 0, 0);
        __syncthreads();
        cur ^= 1;
    }

    // epilogue: lane holds C[r][c..c+3] -> one 8B store per (m,n)
    #pragma unroll
    for (int m = 0; m < 4; ++m) {
        int r = m0 + wm * 64 + m * 16 + (lane & 15);
        if (r < M) {
            #pragma unroll
            for (int n = 0; n < 8; ++n) {
                int cb = ooff + wn * 128 + n * 16 + (lane >> 4) * 4;
                uint2 pk;
                pk.x = ((unsigned int)f2bf(acc[m][n][1]) << 16) | (unsigned int)f2bf(acc[m][n][0]);
                pk.y = ((unsigned int)f2bf(acc[m][n][3]) << 16) | (unsigned int)f2bf(acc[m][n][2]);
                *(uint2*)&U[(size_t)r * 1024 + cb] = pk;
            }
        }
    }
}

// ---------------- fallback GEMM0 (f32 A, reg-staged; k-tiled P, new B staging) --------
__global__ __launch_bounds__(512, 1)
void k_gemm0(const float* __restrict__ Aptr, const unsigned short* __restrict__ P,
             unsigned short* __restrict__ U, int ooff, int M) {
    constexpr int K  = K1P;
    constexpr int KT = K / 32;
    __shared__ unsigned short Al[128 * 32];
    __shared__ unsigned short Bpl[4][HID * 8];

    const int t    = threadIdx.x;
    const int lane = t & 63;
    const int wv   = t >> 6;
    const int wm   = wv >> 2, wn = wv & 3;
    const int m0   = blockIdx.x * 128;

    f32x4 acc[4][8];
    #pragma unroll
    for (int m = 0; m < 4; ++m)
        #pragma unroll
        for (int n = 0; n < 8; ++n)
            acc[m][n] = (f32x4){0.f, 0.f, 0.f, 0.f};

    const int srow = t >> 2, sch = t & 3;
    const bool rok = (m0 + srow) < M;

    for (int kt = 0; kt < KT; ++kt) {
        const int k0 = kt * 32;
        __syncthreads();
        {
            const int gk = k0 + sch * 8;
            su16x8 av;
            float f[8];
            const float* Ab = Aptr + (size_t)(m0 + srow) * FIN + gk;
            if (rok && gk + 8 <= FIN) {
                f32x4u lo = *(const f32x4u*)Ab;
                f32x4u hi = *(const f32x4u*)(Ab + 4);
                f[0]=lo.x; f[1]=lo.y; f[2]=lo.z; f[3]=lo.w;
                f[4]=hi.x; f[5]=hi.y; f[6]=hi.z; f[7]=hi.w;
            } else {
                #pragma unroll
                for (int j = 0; j < 8; ++j)
                    f[j] = (rok && gk + j < FIN) ? Ab[j] : 0.f;
            }
            #pragma unroll
            for (int j = 0; j < 8; ++j) av[j] = f2bf(f[j]);
            *(su16x8*)&Al[srow * 32 + 8 * (sch ^ ((srow >> 1) & 3))] = av;
        }
        {
            const unsigned short* Pb = P + (size_t)kt * 16384 + t * 8;
            #pragma unroll
            for (int q = 0; q < 4; ++q)
                *(su16x8*)&Bpl[q][t * 8] = *(const su16x8*)(Pb + q * 4096);
        }
        __syncthreads();
        bf16x8 af[4], bfr[8];
        #pragma unroll
        for (int m = 0; m < 4; ++m) {
            int r  = wm * 64 + m * 16 + (lane & 15);
            int kq = lane >> 4;
            af[m] = *(const bf16x8*)&Al[r * 32 + 8 * (kq ^ ((r >> 1) & 3))];
        }
        #pragma unroll
        for (int n = 0; n < 8; ++n) {
            int c = wn * 128 + n * 16 + (lane & 15);
            bfr[n] = *(const bf16x8*)&Bpl[lane >> 4][c * 8];
        }
        #pragma unroll
        for (int m = 0; m < 4; ++m)
            #pragma unroll
            for (int n = 0; n < 8; ++n)
                acc[m][n] = __builtin_amdgcn_mfma_f32_16x16x32_bf16(bfr[n], af[m], acc[m][n], 0, 0, 0);
    }

    #pragma unroll
    for (int m = 0; m < 4; ++m) {
        int r = m0 + wm * 64 + m * 16 + (lane & 15);
        if (r < M) {
            #pragma unroll
            for (int n = 0; n < 8; ++n) {
                int cb = ooff + wn * 128 + n * 16 + (lane >> 4) * 4;
                uint2 pk;
                pk.x = ((unsigned int)f2bf(acc[m][n][1]) << 16) | (unsigned int)f2bf(acc[m][n][0]);
                pk.y = ((unsigned int)f2bf(acc[m][n][3]) << 16) | (unsigned int)f2bf(acc[m][n][2]);
                *(uint2*)&U[(size_t)r * 1024 + cb] = pk;
            }
        }
    }
}

// ---------------- aggr: U0[d] += sum_e w_e * U1[src_e]; optional fused bias+relu -------
template<int RELU>
__global__ void k_aggr(unsigned short* U, const int* __restrict__ rowptr,
                       const int* __restrict__ esrc, const int* __restrict__ deg,
                       const float* __restrict__ bias, int M) {
    int wid  = (blockIdx.x * 256 + threadIdx.x) >> 6;
    int lane = threadIdx.x & 63;
    if (wid >= M) return;
    int e0 = rowptr[wid], e1 = rowptr[wid + 1];
    if (RELU == 0 && e0 == e1) return;

    unsigned short* u0 = U + (size_t)wid * 1024 + lane * 8;
    uint4 v0 = *(const uint4*)u0;
    unsigned int a0[4] = {v0.x, v0.y, v0.z, v0.w};
    float acc[8];
    #pragma unroll
    for (int i = 0; i < 4; ++i) {
        acc[2 * i]     = bf2f((unsigned short)(a0[i] & 0xffffu));
        acc[2 * i + 1] = bf2f((unsigned short)(a0[i] >> 16));
    }

    if (e0 < e1) {
        int dd = deg[wid];
        float dr = dd > 0 ? rsqrtf((float)dd) : 0.f;
        for (int e = e0; e < e1; ++e) {
            int s = esrc[e];
            float we = -dr * rsqrtf((float)deg[s]);
            const uint4 v = *(const uint4*)(U + (size_t)s * 1024 + 512 + lane * 8);
            unsigned int uu[4] = {v.x, v.y, v.z, v.w};
            #pragma unroll
            for (int i = 0; i < 4; ++i) {
                acc[2 * i]     += we * bf2f((unsigned short)(uu[i] & 0xffffu));
                acc[2 * i + 1] += we * bf2f((unsigned short)(uu[i] >> 16));
            }
        }
    }

    if (RELU) {
        float4 c0 = *(const float4*)(bias + lane * 8);
        float4 c1 = *(const float4*)(bias + lane * 8 + 4);
        float bb[8] = {c0.x,c0.y,c0.z,c0.w,c1.x,c1.y,c1.z,c1.w};
        #pragma unroll
        for (int i = 0; i < 8; ++i) {
            float f = acc[i] + bb[i];
            acc[i] = f > 0.f ? f : 0.f;
        }
    }
    uint4 w4;
    unsigned int* wo = (unsigned int*)&w4;
    #pragma unroll
    for (int i = 0; i < 4; ++i)
        wo[i] = ((unsigned int)f2bf(acc[2 * i + 1]) << 16) | (unsigned int)f2bf(acc[2 * i]);
    *(uint4*)u0 = w4;
}

// ---------------- fused aggr + final: out[d] = relu(U0[d]+prop+b2) @ Wl + bl ----------
__global__ void k_aggrf(const unsigned short* __restrict__ U, const int* __restrict__ rowptr,
                        const int* __restrict__ esrc, const int* __restrict__ deg,
                        const float* __restrict__ b2, const float* __restrict__ Wl,
                        const float* __restrict__ bl, float* __restrict__ out, int M) {
    int wid  = (blockIdx.x * 256 + threadIdx.x) >> 6;
    int lane = threadIdx.x & 63;
    if (wid >= M) return;
    int e0 = rowptr[wid], e1 = rowptr[wid + 1];

    const uint4 v0 = *(const uint4*)(U + (size_t)wid * 1024 + lane * 8);
    unsigned int a0[4] = {v0.x, v0.y, v0.z, v0.w};
    float acc[8];
    #pragma unroll
    for (int i = 0; i < 4; ++i) {
        acc[2 * i]     = bf2f((unsigned short)(a0[i] & 0xffffu));
        acc[2 * i + 1] = bf2f((unsigned short)(a0[i] >> 16));
    }
    if (e0 < e1) {
        int dd = deg[wid];
        float dr = dd > 0 ? rsqrtf((float)dd) : 0.f;
        for (int e = e0; e < e1; ++e) {
            int s = esrc[e];
            float we = -dr * rsqrtf((float)deg[s]);
            const uint4 v = *(const uint4*)(U + (size_t)s * 1024 + 512 + lane * 8);
            unsigned int uu[4] = {v.x, v.y, v.z, v.w};
            #pragma unroll
            for (int i = 0; i < 4; ++i) {
                acc[2 * i]     += we * bf2f((unsigned short)(uu[i] & 0xffffu));
                acc[2 * i + 1] += we * bf2f((unsigned short)(uu[i] >> 16));
            }
        }
    }
    float4 c0 = *(const float4*)(b2 + lane * 8);
    float4 c1 = *(const float4*)(b2 + lane * 8 + 4);
    float bb[8] = {c0.x,c0.y,c0.z,c0.w,c1.x,c1.y,c1.z,c1.w};
    const float4* Wp = reinterpret_cast<const float4*>(Wl + lane * 16);
    float4 w0 = Wp[0], w1 = Wp[1], w2 = Wp[2], w3 = Wp[3];
    float wv[16] = {w0.x, w0.y, w0.z, w0.w, w1.x, w1.y, w1.z, w1.w,
                    w2.x, w2.y, w2.z, w2.w, w3.x, w3.y, w3.z, w3.w};
    float s0 = 0.f, s1 = 0.f;
    #pragma unroll
    for (int i = 0; i < 8; ++i) {
        float f = acc[i] + bb[i];
        f = f > 0.f ? f : 0.f;
        s0 += f * wv[2 * i];
        s1 += f * wv[2 * i + 1];
    }
    #pragma unroll
    for (int off = 32; off; off >>= 1) {
        s0 += __shfl_xor(s0, off, 64);
        s1 += __shfl_xor(s1, off, 64);
    }
    if (lane == 0) {
        out[2 * (size_t)wid]     = s0 + bl[0];
        out[2 * (size_t)wid + 1] = s1 + bl[1];
    }
}

// ---------------- fallback final (when esrc lives in d_out) ----------------
__global__ void k_final(const unsigned short* __restrict__ U, const float* __restrict__ b2,
                        const float* __restrict__ Wl, const float* __restrict__ bl,
                        float* __restrict__ out, int M) {
    int wid  = (blockIdx.x * 256 + threadIdx.x) >> 6;
    int lane = threadIdx.x & 63;
    if (wid >= M) return;
    const uint4 v = *(const uint4*)(U + (size_t)wid * 1024 + lane * 8);
    float4 c0 = *(const float4*)(b2 + lane * 8);
    float4 c1 = *(const float4*)(b2 + lane * 8 + 4);
    float bb[8] = {c0.x,c0.y,c0.z,c0.w,c1.x,c1.y,c1.z,c1.w};
    const float4* Wp = reinterpret_cast<const float4*>(Wl + lane * 16);
    float4 w0 = Wp[0], w1 = Wp[1], w2 = Wp[2], w3 = Wp[3];
    float wv[16] = {w0.x, w0.y, w0.z, w0.w, w1.x, w1.y, w1.z, w1.w,
                    w2.x, w2.y, w2.z, w2.w, w3.x, w3.y, w3.z, w3.w};
    unsigned int uu[4] = {v.x, v.y, v.z, v.w};
    float s0 = 0.f, s1 = 0.f;
    #pragma unroll
    for (int j = 0; j < 4; ++j) {
        float f0 = bf2f((unsigned short)(uu[j] & 0xffffu)) + bb[2 * j];
        float f1 = bf2f((unsigned short)(uu[j] >> 16))     + bb[2 * j + 1];
        f0 = f0 > 0.f ? f0 : 0.f;
        f1 = f1 > 0.f ? f1 : 0.f;
        s0 += f0 * wv[4 * j + 0];
        s1 += f0 * wv[4 * j + 1];
        s0 += f1 * wv[4 * j + 2];
        s1 += f1 * wv[4 * j + 3];
    }
    #pragma unroll
    for (int off = 32; off; off >>= 1) {
        s0 += __shfl_xor(s0, off, 64);
        s1 += __shfl_xor(s1, off, 64);
    }
    if (lane == 0) {
        out[2 * (size_t)wid]     = s0 + bl[0];
        out[2 * (size_t)wid + 1] = s1 + bl[1];
    }
}

extern "C" void kernel_launch(void* const* d_in, const int* in_sizes, int n_in,
                              void* d_out, int out_size, void* d_ws, size_t ws_size,
                              hipStream_t stream) {
    const float* x    = (const float*)d_in[0];
    const int*   ei   = (const int*)d_in[1];
    const float* W1_0 = (const float*)d_in[2];
    const float* W1_1 = (const float*)d_in[3];
    const float* b1   = (const float*)d_in[4];
    const float* W2_0 = (const float*)d_in[5];
    const float* W2_1 = (const float*)d_in[6];
    const float* b2   = (const float*)d_in[7];
    const float* Wl   = (const float*)d_in[8];
    const float* bl   = (const float*)d_in[9];
    const int* src = ei;
    const int* dst = ei + NEDGES;
    float* out = (float*)d_out;

    char* ws = (char*)d_ws;
    size_t off = 0;
    auto alloc = [&](size_t bytes) -> void* {
        void* p = ws + off;
        off += (bytes + 255) & ~(size_t)255;
        return p;
    };
    int*            deg    = (int*)alloc((size_t)NNODES * 4);
    int*            cnt    = (int*)alloc((size_t)NNODES * 4);
    int*            rowptr = (int*)alloc((size_t)(NNODES + 1) * 4);
    int*            btot   = (int*)alloc((size_t)NB * 4);
    unsigned short* P1     = (unsigned short*)alloc((size_t)2 * K1P * HID * 2); // 2 panels
    unsigned short* P2     = (unsigned short*)alloc((size_t)2 * HID * HID * 2); // 2 panels
    unsigned short* U      = (unsigned short*)alloc((size_t)NNODES * 1024 * 2);

    bool esrc_ws = (off + (size_t)NEDGES * 4 <= ws_size);
    int* esrc = esrc_ws ? (int*)alloc((size_t)NEDGES * 4) : (int*)d_out;
    bool have_xb = (off + (size_t)NNODES * K1P * 2 <= ws_size);
    unsigned short* xb = have_xb ? (unsigned short*)alloc((size_t)NNODES * K1P * 2) : nullptr;

    hipMemsetAsync(deg, 0, (size_t)NNODES * 4, stream);
    hipMemsetAsync(cnt, 0, (size_t)NNODES * 4, stream);

    // CSR build + degrees
    k_deg    <<<(NEDGES + 255) / 256, 256, 0, stream>>>(src, dst, deg, cnt, NEDGES);
    k_scan1  <<<NB, 256, 0, stream>>>(cnt, btot, NNODES);
    k_scan2  <<<1, 1024, 0, stream>>>(btot, NB);
    k_scan3  <<<NB, 256, 0, stream>>>(cnt, btot, rowptr, NNODES, NEDGES);
    k_scatter<<<(NEDGES + 255) / 256, 256, 0, stream>>>(src, dst, rowptr, cnt, esrc, NEDGES);

    // k-tiled weight panels
    const int pg1 = (K1P * HID + 255) / 256, pg2 = (HID * HID + 255) / 256;
    k_buildP<<<pg1, 256, 0, stream>>>(W1_0, P1, K1P, FIN);
    k_buildP<<<pg1, 256, 0, stream>>>(W1_1, P1 + (size_t)K1P * HID, K1P, FIN);
    k_buildP<<<pg2, 256, 0, stream>>>(W2_0, P2, HID, HID);
    k_buildP<<<pg2, 256, 0, stream>>>(W2_1, P2 + (size_t)HID * HID, HID, HID);

    const int nblk = (NNODES + 127) / 128;

    // layer 1: U = x @ [W1_0|W1_1]
    if (have_xb) {
        k_xcvt<<<(int)(((long)NNODES * K1P / 8 + 255) / 256), 256, 0, stream>>>(x, xb);
        k_gemmt<K1P, K1P><<<nblk, 512, 0, stream>>>(xb, P1, U, 0, NNODES);
        k_gemmt<K1P, K1P><<<nblk, 512, 0, stream>>>(xb, P1 + (size_t)K1P * HID, U, 512, NNODES);
    } else {
        k_gemm0<<<nblk, 512, 0, stream>>>(x, P1, U, 0, NNODES);
        k_gemm0<<<nblk, 512, 0, stream>>>(x, P1 + (size_t)K1P * HID, U, 512, NNODES);
    }
    // aggr folds prop + bias + relu -> U0 = h1
    k_aggr<1><<<NNODES / 4, 256, 0, stream>>>(U, rowptr, esrc, deg, b1, NNODES);

    // layer 2: U1 <- h1@W2_1 first, then U0 <- h1@W2_0 (in-place)
    k_gemmt<HID, 1024><<<nblk, 512, 0, stream>>>(U, P2 + (size_t)HID * HID, U, 512, NNODES);
    k_gemmt<HID, 1024><<<nblk, 512, 0, stream>>>(U, P2, U, 0, NNODES);

    // prop + bias + relu + final GEMV
    if (esrc_ws) {
        k_aggrf<<<NNODES / 4, 256, 0, stream>>>(U, rowptr, esrc, deg, b2, Wl, bl, out, NNODES);
    } else {
        k_aggr<0><<<NNODES / 4, 256, 0, stream>>>(U, rowptr, esrc, deg, nullptr, NNODES);
        k_final<<<NNODES / 4, 256, 0, stream>>>(U, b2, Wl, bl, out, NNODES);
    }
}

// Round 8
// 1047.245 us; speedup vs baseline: 1.2603x; 1.0447x over previous
//
#include <hip/hip_runtime.h>

#define NNODES 200000
#define MPAD   200064   // NNODES rounded up to 128
#define NEDGES 400000
#define FIN    165
#define K1P    192      // FIN padded to 6 x 32
#define HID    512
#define NB     ((NNODES + 255) / 256)   // 782 scan blocks

typedef __bf16 bf16_t;
typedef __bf16 bf16x8 __attribute__((ext_vector_type(8)));
typedef float  f32x4  __attribute__((ext_vector_type(4)));
typedef unsigned short su16x8 __attribute__((ext_vector_type(8)));
typedef float f32x4u __attribute__((ext_vector_type(4), aligned(4)));

static __device__ __forceinline__ float bf2f(unsigned short u) {
    unsigned int x = ((unsigned int)u) << 16;
    return __builtin_bit_cast(float, x);
}
static __device__ __forceinline__ unsigned short f2bf(float f) {
    bf16_t h = (bf16_t)f;  // RNE
    return __builtin_bit_cast(unsigned short, h);
}
// async global->LDS, 16B per lane (dest = wave-uniform base + lane*16)
static __device__ __forceinline__ void gl_lds16(const void* g, void* l) {
    __builtin_amdgcn_global_load_lds(
        (const __attribute__((address_space(1))) unsigned int*)g,
        (__attribute__((address_space(3))) unsigned int*)l, 16, 0, 0);
}

// ---------------- degree histograms ----------------
__global__ void k_deg(const int* __restrict__ src, const int* __restrict__ dst,
                      int* __restrict__ deg, int* __restrict__ cnt, int E) {
    int e = blockIdx.x * 256 + threadIdx.x;
    if (e < E) {
        atomicAdd(&deg[src[e]], 1);
        atomicAdd(&cnt[dst[e]], 1);
    }
}

// ---------------- CSR build: 2-level exclusive scan ----------------
__global__ void k_scan1(int* __restrict__ cnt, int* __restrict__ btot, int n) {
    __shared__ int s[256];
    int i = blockIdx.x * 256 + threadIdx.x;
    int v = (i < n) ? cnt[i] : 0;
    s[threadIdx.x] = v;
    __syncthreads();
    #pragma unroll
    for (int off = 1; off < 256; off <<= 1) {
        int t = (threadIdx.x >= off) ? s[threadIdx.x - off] : 0;
        __syncthreads();
        s[threadIdx.x] += t;
        __syncthreads();
    }
    if (i < n) cnt[i] = s[threadIdx.x] - v;
    if (threadIdx.x == 255) btot[blockIdx.x] = s[255];
}

__global__ void k_scan2(int* __restrict__ btot, int nb) {
    __shared__ int s[1024];
    int i = threadIdx.x;
    int v = (i < nb) ? btot[i] : 0;
    s[i] = v;
    __syncthreads();
    #pragma unroll
    for (int off = 1; off < 1024; off <<= 1) {
        int t = (i >= off) ? s[i - off] : 0;
        __syncthreads();
        s[i] += t;
        __syncthreads();
    }
    if (i < nb) btot[i] = s[i] - v;
}

__global__ void k_scan3(int* __restrict__ cnt, const int* __restrict__ btot,
                        int* __restrict__ rowptr, int n, int E) {
    int i = blockIdx.x * 256 + threadIdx.x;
    if (i < n) {
        rowptr[i] = cnt[i] + btot[blockIdx.x];
        cnt[i] = 0;
    }
    if (i == 0) rowptr[n] = E;
}

__global__ void k_scatter(const int* __restrict__ src, const int* __restrict__ dst,
                          const int* __restrict__ rowptr, int* __restrict__ cur,
                          int* __restrict__ esrc, int E) {
    int e = blockIdx.x * 256 + threadIdx.x;
    if (e < E) {
        int d = dst[e];
        int pos = rowptr[d] + atomicAdd(&cur[d], 1);
        esrc[pos] = src[e];
    }
}

// ---------------- build k-tiled bf16 B panel: P[kt][q][n][j] = W[kt*32+q*8+j][n] -------
__global__ void k_buildP(const float* __restrict__ W, unsigned short* __restrict__ P,
                         int kp, int kfull) {
    int idx = blockIdx.x * 256 + threadIdx.x;
    if (idx >= kp * HID) return;
    int j  = idx & 7;
    int n  = (idx >> 3) & 511;
    int q  = (idx >> 12) & 3;
    int kt = idx >> 14;
    int k  = kt * 32 + q * 8 + j;
    P[idx] = (k < kfull) ? f2bf(W[(size_t)k * HID + n]) : (unsigned short)0;
}

// ---------------- x -> bf16 padded [MPAD x 192] ----------------
__global__ void k_xcvt(const float* __restrict__ x, unsigned short* __restrict__ xb) {
    long i = ((long)blockIdx.x * 256 + threadIdx.x) * 8;
    if (i >= (long)NNODES * K1P) return;
    int row = (int)(i / K1P), k = (int)(i % K1P);
    const float* xr = x + (size_t)row * FIN;
    __align__(16) unsigned short v[8];
    #pragma unroll
    for (int j = 0; j < 8; ++j)
        v[j] = (k + j < FIN) ? f2bf(xr[k + j]) : (unsigned short)0;
    *(su16x8*)&xb[i] = *(su16x8*)v;
}

// ---------------- k_gemms: 128x128-tile m97-style GEMM, n-split grid ----------------
// grid = (4*npanels, nblk). Block (bx,by): panel=bx>>2, 128-col slice (bx&3), rows by*128.
// Single-buffered 16KB LDS, 4 waves, gload_lds staging, swapped-operand MFMA, 8B stores.
// A rows up to MPAD must be readable (padded allocs); stores cover padded rows (owned).
template<int K, int LDA>
__global__ __launch_bounds__(256, 4)
void k_gemms(const unsigned short* __restrict__ A, const unsigned short* __restrict__ P,
             unsigned short* __restrict__ U, int obase) {
    constexpr int KT = K / 32;
    __shared__ unsigned short Al[128 * 32];     // 8 KB
    __shared__ unsigned short Bl[4 * 128 * 8];  // 8 KB: 4 q-planes x 128 cols x 8

    const int t    = threadIdx.x;
    const int lane = t & 63;
    const int wv   = t >> 6;
    const int wm   = wv >> 1, wn = wv & 1;
    const int panel = blockIdx.x >> 2;
    const int ncol  = (blockIdx.x & 3) * 128;
    const int m0    = blockIdx.y * 128;
    const unsigned short* Pb = P + (size_t)panel * K * 512 + ncol * 8;
    const int oc = obase + panel * 512 + ncol;

    const int arow = t >> 2, ach = t & 3;
    const unsigned short* Ab = A + (size_t)m0 * LDA;

    f32x4 acc[4][4];
    #pragma unroll
    for (int m = 0; m < 4; ++m)
        #pragma unroll
        for (int n = 0; n < 4; ++n)
            acc[m][n] = (f32x4){0.f, 0.f, 0.f, 0.f};

    for (int kt = 0; kt < KT; ++kt) {
        __syncthreads();   // all waves done reading previous tile
        #pragma unroll
        for (int i = 0; i < 2; ++i) {   // stage A: rows (t>>2)+i*64, chunk swizzled
            int r = arow + i * 64;
            gl_lds16(Ab + (size_t)r * LDA + kt * 32 + (ach ^ ((r >> 1) & 3)) * 8,
                     &Al[t * 8 + i * 2048]);
        }
        #pragma unroll
        for (int i = 0; i < 2; ++i)     // stage B: wave wv -> q-plane wv, contiguous
            gl_lds16(Pb + (size_t)kt * 16384 + wv * 4096 + lane * 8 + i * 512,
                     &Bl[wv * 1024 + lane * 8 + i * 512]);
        __syncthreads();   // staged data visible (vmcnt0 + barrier)

        bf16x8 af[4], bfr[4];
        const int kq = lane >> 4;
        #pragma unroll
        for (int m = 0; m < 4; ++m) {
            int r = wm * 64 + m * 16 + (lane & 15);
            af[m] = *(const bf16x8*)&Al[r * 32 + 8 * (kq ^ ((r >> 1) & 3))];
        }
        #pragma unroll
        for (int n = 0; n < 4; ++n) {
            int c = wn * 64 + n * 16 + (lane & 15);
            bfr[n] = *(const bf16x8*)&Bl[kq * 1024 + c * 8];
        }
        #pragma unroll
        for (int m = 0; m < 4; ++m)
            #pragma unroll
            for (int n = 0; n < 4; ++n)
                acc[m][n] = __builtin_amdgcn_mfma_f32_16x16x32_bf16(bfr[n], af[m], acc[m][n], 0, 0, 0);
    }

    // epilogue: lane holds C[r][cb..cb+3] -> 8B store per (m,n); padded rows owned
    #pragma unroll
    for (int m = 0; m < 4; ++m) {
        int r = m0 + wm * 64 + m * 16 + (lane & 15);
        #pragma unroll
        for (int n = 0; n < 4; ++n) {
            int cb = oc + wn * 64 + n * 16 + (lane >> 4) * 4;
            uint2 pk;
            pk.x = ((unsigned int)f2bf(acc[m][n][1]) << 16) | (unsigned int)f2bf(acc[m][n][0]);
            pk.y = ((unsigned int)f2bf(acc[m][n][3]) << 16) | (unsigned int)f2bf(acc[m][n][2]);
            *(uint2*)&U[(size_t)r * 1024 + cb] = pk;
        }
    }
}

// ---------------- k_gemmw: full-width K=512 (round-7 proven) — for in-place U0 pass ----
__global__ __launch_bounds__(512, 1)
void k_gemmw(const unsigned short* __restrict__ A, const unsigned short* __restrict__ P,
             unsigned short* __restrict__ U, int ooff, int M) {
    constexpr int KT = HID / 32;
    __shared__ unsigned short Al[2][128 * 32];
    __shared__ unsigned short Bl[2][4][HID * 8];

    const int t    = threadIdx.x;
    const int lane = t & 63;
    const int wv   = t >> 6;
    const int wm   = wv >> 2, wn = wv & 3;
    const int m0   = blockIdx.x * 128;

    const int srow = t >> 2;
    const int gch  = ((t & 3) ^ ((srow >> 1) & 3)) * 8;
    const unsigned short* Ab = A + (size_t)(m0 + srow) * 1024 + gch;
    const bool rok = (m0 + srow) < M;
    const unsigned short* Pb = P + (size_t)t * 8;

    f32x4 acc[4][8];
    #pragma unroll
    for (int m = 0; m < 4; ++m)
        #pragma unroll
        for (int n = 0; n < 8; ++n)
            acc[m][n] = (f32x4){0.f, 0.f, 0.f, 0.f};

    if (rok) gl_lds16(Ab, &Al[0][t * 8]);
    #pragma unroll
    for (int q = 0; q < 4; ++q) gl_lds16(Pb + q * 4096, &Bl[0][q][t * 8]);
    __syncthreads();

    int cur = 0;
    for (int kt = 0; kt < KT; ++kt) {
        if (kt + 1 < KT) {
            if (rok) gl_lds16(Ab + (kt + 1) * 32, &Al[cur ^ 1][t * 8]);
            const unsigned short* Pn = Pb + (size_t)(kt + 1) * 16384;
            #pragma unroll
            for (int q = 0; q < 4; ++q)
                gl_lds16(Pn + q * 4096, &Bl[cur ^ 1][q][t * 8]);
        }
        bf16x8 af[4], bfr[8];
        #pragma unroll
        for (int m = 0; m < 4; ++m) {
            int r  = wm * 64 + m * 16 + (lane & 15);
            int kq = lane >> 4;
            af[m] = *(const bf16x8*)&Al[cur][r * 32 + 8 * (kq ^ ((r >> 1) & 3))];
        }
        #pragma unroll
        for (int n = 0; n < 8; ++n) {
            int c = wn * 128 + n * 16 + (lane & 15);
            bfr[n] = *(const bf16x8*)&Bl[cur][lane >> 4][c * 8];
        }
        #pragma unroll
        for (int m = 0; m < 4; ++m)
            #pragma unroll
            for (int n = 0; n < 8; ++n)
                acc[m][n] = __builtin_amdgcn_mfma_f32_16x16x32_bf16(bfr[n], af[m], acc[m][n], 0, 0, 0);
        __syncthreads();
        cur ^= 1;
    }

    #pragma unroll
    for (int m = 0; m < 4; ++m) {
        int r = m0 + wm * 64 + m * 16 + (lane & 15);
        if (r < M) {
            #pragma unroll
            for (int n = 0; n < 8; ++n) {
                int cb = ooff + wn * 128 + n * 16 + (lane >> 4) * 4;
                uint2 pk;
                pk.x = ((unsigned int)f2bf(acc[m][n][1]) << 16) | (unsigned int)f2bf(acc[m][n][0]);
                pk.y = ((unsigned int)f2bf(acc[m][n][3]) << 16) | (unsigned int)f2bf(acc[m][n][2]);
                *(uint2*)&U[(size_t)r * 1024 + cb] = pk;
            }
        }
    }
}

// ---------------- fallback GEMM0 (f32 A, reg-staged) ----------------
__global__ __launch_bounds__(512, 1)
void k_gemm0(const float* __restrict__ Aptr, const unsigned short* __restrict__ P,
             unsigned short* __restrict__ U, int ooff, int M) {
    constexpr int K  = K1P;
    constexpr int KT = K / 32;
    __shared__ unsigned short Al[128 * 32];
    __shared__ unsigned short Bpl[4][HID * 8];

    const int t    = threadIdx.x;
    const int lane = t & 63;
    const int wv   = t >> 6;
    const int wm   = wv >> 2, wn = wv & 3;
    const int m0   = blockIdx.x * 128;

    f32x4 acc[4][8];
    #pragma unroll
    for (int m = 0; m < 4; ++m)
        #pragma unroll
        for (int n = 0; n < 8; ++n)
            acc[m][n] = (f32x4){0.f, 0.f, 0.f, 0.f};

    const int srow = t >> 2, sch = t & 3;
    const bool rok = (m0 + srow) < M;

    for (int kt = 0; kt < KT; ++kt) {
        const int k0 = kt * 32;
        __syncthreads();
        {
            const int gk = k0 + sch * 8;
            su16x8 av;
            float f[8];
            const float* Ab = Aptr + (size_t)(m0 + srow) * FIN + gk;
            if (rok && gk + 8 <= FIN) {
                f32x4u lo = *(const f32x4u*)Ab;
                f32x4u hi = *(const f32x4u*)(Ab + 4);
                f[0]=lo.x; f[1]=lo.y; f[2]=lo.z; f[3]=lo.w;
                f[4]=hi.x; f[5]=hi.y; f[6]=hi.z; f[7]=hi.w;
            } else {
                #pragma unroll
                for (int j = 0; j < 8; ++j)
                    f[j] = (rok && gk + j < FIN) ? Ab[j] : 0.f;
            }
            #pragma unroll
            for (int j = 0; j < 8; ++j) av[j] = f2bf(f[j]);
            *(su16x8*)&Al[srow * 32 + 8 * (sch ^ ((srow >> 1) & 3))] = av;
        }
        {
            const unsigned short* Pb = P + (size_t)kt * 16384 + t * 8;
            #pragma unroll
            for (int q = 0; q < 4; ++q)
                *(su16x8*)&Bpl[q][t * 8] = *(const su16x8*)(Pb + q * 4096);
        }
        __syncthreads();
        bf16x8 af[4], bfr[8];
        #pragma unroll
        for (int m = 0; m < 4; ++m) {
            int r  = wm * 64 + m * 16 + (lane & 15);
            int kq = lane >> 4;
            af[m] = *(const bf16x8*)&Al[r * 32 + 8 * (kq ^ ((r >> 1) & 3))];
        }
        #pragma unroll
        for (int n = 0; n < 8; ++n) {
            int c = wn * 128 + n * 16 + (lane & 15);
            bfr[n] = *(const bf16x8*)&Bpl[lane >> 4][c * 8];
        }
        #pragma unroll
        for (int m = 0; m < 4; ++m)
            #pragma unroll
            for (int n = 0; n < 8; ++n)
                acc[m][n] = __builtin_amdgcn_mfma_f32_16x16x32_bf16(bfr[n], af[m], acc[m][n], 0, 0, 0);
    }

    #pragma unroll
    for (int m = 0; m < 4; ++m) {
        int r = m0 + wm * 64 + m * 16 + (lane & 15);
        if (r < M) {
            #pragma unroll
            for (int n = 0; n < 8; ++n) {
                int cb = ooff + wn * 128 + n * 16 + (lane >> 4) * 4;
                uint2 pk;
                pk.x = ((unsigned int)f2bf(acc[m][n][1]) << 16) | (unsigned int)f2bf(acc[m][n][0]);
                pk.y = ((unsigned int)f2bf(acc[m][n][3]) << 16) | (unsigned int)f2bf(acc[m][n][2]);
                *(uint2*)&U[(size_t)r * 1024 + cb] = pk;
            }
        }
    }
}

// ---------------- aggr: U0[d] += sum_e w_e * U1[src_e]; optional fused bias+relu -------
template<int RELU>
__global__ void k_aggr(unsigned short* U, const int* __restrict__ rowptr,
                       const int* __restrict__ esrc, const int* __restrict__ deg,
                       const float* __restrict__ bias, int M) {
    int wid  = (blockIdx.x * 256 + threadIdx.x) >> 6;
    int lane = threadIdx.x & 63;
    if (wid >= M) return;
    int e0 = rowptr[wid], e1 = rowptr[wid + 1];
    if (RELU == 0 && e0 == e1) return;

    unsigned short* u0 = U + (size_t)wid * 1024 + lane * 8;
    uint4 v0 = *(const uint4*)u0;
    unsigned int a0[4] = {v0.x, v0.y, v0.z, v0.w};
    float acc[8];
    #pragma unroll
    for (int i = 0; i < 4; ++i) {
        acc[2 * i]     = bf2f((unsigned short)(a0[i] & 0xffffu));
        acc[2 * i + 1] = bf2f((unsigned short)(a0[i] >> 16));
    }

    if (e0 < e1) {
        int dd = deg[wid];
        float dr = dd > 0 ? rsqrtf((float)dd) : 0.f;
        for (int e = e0; e < e1; ++e) {
            int s = esrc[e];
            float we = -dr * rsqrtf((float)deg[s]);
            const uint4 v = *(const uint4*)(U + (size_t)s * 1024 + 512 + lane * 8);
            unsigned int uu[4] = {v.x, v.y, v.z, v.w};
            #pragma unroll
            for (int i = 0; i < 4; ++i) {
                acc[2 * i]     += we * bf2f((unsigned short)(uu[i] & 0xffffu));
                acc[2 * i + 1] += we * bf2f((unsigned short)(uu[i] >> 16));
            }
        }
    }

    if (RELU) {
        float4 c0 = *(const float4*)(bias + lane * 8);
        float4 c1 = *(const float4*)(bias + lane * 8 + 4);
        float bb[8] = {c0.x,c0.y,c0.z,c0.w,c1.x,c1.y,c1.z,c1.w};
        #pragma unroll
        for (int i = 0; i < 8; ++i) {
            float f = acc[i] + bb[i];
            acc[i] = f > 0.f ? f : 0.f;
        }
    }
    uint4 w4;
    unsigned int* wo = (unsigned int*)&w4;
    #pragma unroll
    for (int i = 0; i < 4; ++i)
        wo[i] = ((unsigned int)f2bf(acc[2 * i + 1]) << 16) | (unsigned int)f2bf(acc[2 * i]);
    *(uint4*)u0 = w4;
}

// ---------------- fused aggr + final: out[d] = relu(U0[d]+prop+b2) @ Wl + bl ----------
__global__ void k_aggrf(const unsigned short* __restrict__ U, const int* __restrict__ rowptr,
                        const int* __restrict__ esrc, const int* __restrict__ deg,
                        const float* __restrict__ b2, const float* __restrict__ Wl,
                        const float* __restrict__ bl, float* __restrict__ out, int M) {
    int wid  = (blockIdx.x * 256 + threadIdx.x) >> 6;
    int lane = threadIdx.x & 63;
    if (wid >= M) return;
    int e0 = rowptr[wid], e1 = rowptr[wid + 1];

    const uint4 v0 = *(const uint4*)(U + (size_t)wid * 1024 + lane * 8);
    unsigned int a0[4] = {v0.x, v0.y, v0.z, v0.w};
    float acc[8];
    #pragma unroll
    for (int i = 0; i < 4; ++i) {
        acc[2 * i]     = bf2f((unsigned short)(a0[i] & 0xffffu));
        acc[2 * i + 1] = bf2f((unsigned short)(a0[i] >> 16));
    }
    if (e0 < e1) {
        int dd = deg[wid];
        float dr = dd > 0 ? rsqrtf((float)dd) : 0.f;
        for (int e = e0; e < e1; ++e) {
            int s = esrc[e];
            float we = -dr * rsqrtf((float)deg[s]);
            const uint4 v = *(const uint4*)(U + (size_t)s * 1024 + 512 + lane * 8);
            unsigned int uu[4] = {v.x, v.y, v.z, v.w};
            #pragma unroll
            for (int i = 0; i < 4; ++i) {
                acc[2 * i]     += we * bf2f((unsigned short)(uu[i] & 0xffffu));
                acc[2 * i + 1] += we * bf2f((unsigned short)(uu[i] >> 16));
            }
        }
    }
    float4 c0 = *(const float4*)(b2 + lane * 8);
    float4 c1 = *(const float4*)(b2 + lane * 8 + 4);
    float bb[8] = {c0.x,c0.y,c0.z,c0.w,c1.x,c1.y,c1.z,c1.w};
    const float4* Wp = reinterpret_cast<const float4*>(Wl + lane * 16);
    float4 w0 = Wp[0], w1 = Wp[1], w2 = Wp[2], w3 = Wp[3];
    float wv[16] = {w0.x, w0.y, w0.z, w0.w, w1.x, w1.y, w1.z, w1.w,
                    w2.x, w2.y, w2.z, w2.w, w3.x, w3.y, w3.z, w3.w};
    float s0 = 0.f, s1 = 0.f;
    #pragma unroll
    for (int i = 0; i < 8; ++i) {
        float f = acc[i] + bb[i];
        f = f > 0.f ? f : 0.f;
        s0 += f * wv[2 * i];
        s1 += f * wv[2 * i + 1];
    }
    #pragma unroll
    for (int off = 32; off; off >>= 1) {
        s0 += __shfl_xor(s0, off, 64);
        s1 += __shfl_xor(s1, off, 64);
    }
    if (lane == 0) {
        out[2 * (size_t)wid]     = s0 + bl[0];
        out[2 * (size_t)wid + 1] = s1 + bl[1];
    }
}

// ---------------- fallback final (when esrc lives in d_out) ----------------
__global__ void k_final(const unsigned short* __restrict__ U, const float* __restrict__ b2,
                        const float* __restrict__ Wl, const float* __restrict__ bl,
                        float* __restrict__ out, int M) {
    int wid  = (blockIdx.x * 256 + threadIdx.x) >> 6;
    int lane = threadIdx.x & 63;
    if (wid >= M) return;
    const uint4 v = *(const uint4*)(U + (size_t)wid * 1024 + lane * 8);
    float4 c0 = *(const float4*)(b2 + lane * 8);
    float4 c1 = *(const float4*)(b2 + lane * 8 + 4);
    float bb[8] = {c0.x,c0.y,c0.z,c0.w,c1.x,c1.y,c1.z,c1.w};
    const float4* Wp = reinterpret_cast<const float4*>(Wl + lane * 16);
    float4 w0 = Wp[0], w1 = Wp[1], w2 = Wp[2], w3 = Wp[3];
    float wv[16] = {w0.x, w0.y, w0.z, w0.w, w1.x, w1.y, w1.z, w1.w,
                    w2.x, w2.y, w2.z, w2.w, w3.x, w3.y, w3.z, w3.w};
    unsigned int uu[4] = {v.x, v.y, v.z, v.w};
    float s0 = 0.f, s1 = 0.f;
    #pragma unroll
    for (int j = 0; j < 4; ++j) {
        float f0 = bf2f((unsigned short)(uu[j] & 0xffffu)) + bb[2 * j];
        float f1 = bf2f((unsigned short)(uu[j] >> 16))     + bb[2 * j + 1];
        f0 = f0 > 0.f ? f0 : 0.f;
        f1 = f1 > 0.f ? f1 : 0.f;
        s0 += f0 * wv[4 * j + 0];
        s1 += f0 * wv[4 * j + 1];
        s0 += f1 * wv[4 * j + 2];
        s1 += f1 * wv[4 * j + 3];
    }
    #pragma unroll
    for (int off = 32; off; off >>= 1) {
        s0 += __shfl_xor(s0, off, 64);
        s1 += __shfl_xor(s1, off, 64);
    }
    if (lane == 0) {
        out[2 * (size_t)wid]     = s0 + bl[0];
        out[2 * (size_t)wid + 1] = s1 + bl[1];
    }
}

extern "C" void kernel_launch(void* const* d_in, const int* in_sizes, int n_in,
                              void* d_out, int out_size, void* d_ws, size_t ws_size,
                              hipStream_t stream) {
    const float* x    = (const float*)d_in[0];
    const int*   ei   = (const int*)d_in[1];
    const float* W1_0 = (const float*)d_in[2];
    const float* W1_1 = (const float*)d_in[3];
    const float* b1   = (const float*)d_in[4];
    const float* W2_0 = (const float*)d_in[5];
    const float* W2_1 = (const float*)d_in[6];
    const float* b2   = (const float*)d_in[7];
    const float* Wl   = (const float*)d_in[8];
    const float* bl   = (const float*)d_in[9];
    const int* src = ei;
    const int* dst = ei + NEDGES;
    float* out = (float*)d_out;

    char* ws = (char*)d_ws;
    size_t off = 0;
    auto alloc = [&](size_t bytes) -> void* {
        void* p = ws + off;
        off += (bytes + 255) & ~(size_t)255;
        return p;
    };
    int*            deg    = (int*)alloc((size_t)NNODES * 4);
    int*            cnt    = (int*)alloc((size_t)NNODES * 4);
    int*            rowptr = (int*)alloc((size_t)(NNODES + 1) * 4);
    int*            btot   = (int*)alloc((size_t)NB * 4);
    unsigned short* P1     = (unsigned short*)alloc((size_t)2 * K1P * HID * 2);
    unsigned short* P2     = (unsigned short*)alloc((size_t)2 * HID * HID * 2);
    unsigned short* U      = (unsigned short*)alloc((size_t)MPAD * 1024 * 2);  // padded rows

    bool esrc_ws = (off + (size_t)NEDGES * 4 <= ws_size);
    int* esrc = esrc_ws ? (int*)alloc((size_t)NEDGES * 4) : (int*)d_out;
    bool have_xb = (off + (size_t)MPAD * K1P * 2 <= ws_size);
    unsigned short* xb = have_xb ? (unsigned short*)alloc((size_t)MPAD * K1P * 2) : nullptr;

    hipMemsetAsync(deg, 0, (size_t)NNODES * 4, stream);
    hipMemsetAsync(cnt, 0, (size_t)NNODES * 4, stream);

    // CSR build + degrees
    k_deg    <<<(NEDGES + 255) / 256, 256, 0, stream>>>(src, dst, deg, cnt, NEDGES);
    k_scan1  <<<NB, 256, 0, stream>>>(cnt, btot, NNODES);
    k_scan2  <<<1, 1024, 0, stream>>>(btot, NB);
    k_scan3  <<<NB, 256, 0, stream>>>(cnt, btot, rowptr, NNODES, NEDGES);
    k_scatter<<<(NEDGES + 255) / 256, 256, 0, stream>>>(src, dst, rowptr, cnt, esrc, NEDGES);

    // k-tiled weight panels
    const int pg1 = (K1P * HID + 255) / 256, pg2 = (HID * HID + 255) / 256;
    k_buildP<<<pg1, 256, 0, stream>>>(W1_0, P1, K1P, FIN);
    k_buildP<<<pg1, 256, 0, stream>>>(W1_1, P1 + (size_t)K1P * HID, K1P, FIN);
    k_buildP<<<pg2, 256, 0, stream>>>(W2_0, P2, HID, HID);
    k_buildP<<<pg2, 256, 0, stream>>>(W2_1, P2 + (size_t)HID * HID, HID, HID);

    const int nblk = MPAD / 128;  // 1563

    // layer 1: U = x @ [W1_0|W1_1]  (both panels in one n-split dispatch)
    if (have_xb) {
        k_xcvt<<<(int)(((long)NNODES * K1P / 8 + 255) / 256), 256, 0, stream>>>(x, xb);
        k_gemms<K1P, K1P><<<dim3(8, nblk), 256, 0, stream>>>(xb, P1, U, 0);
    } else {
        k_gemm0<<<nblk, 512, 0, stream>>>(x, P1, U, 0, NNODES);
        k_gemm0<<<nblk, 512, 0, stream>>>(x, P1 + (size_t)K1P * HID, U, 512, NNODES);
    }
    // aggr folds prop + bias + relu -> U0 = h1
    k_aggr<1><<<NNODES / 4, 256, 0, stream>>>(U, rowptr, esrc, deg, b1, NNODES);

    // layer 2: U1 <- h1@W2_1 (n-split, reads U0-half only: alias-safe);
    //          U0 <- h1@W2_0 (full-width proven kernel, true in-place)
    k_gemms<HID, 1024><<<dim3(4, nblk), 256, 0, stream>>>(U, P2 + (size_t)HID * HID, U, 512);
    k_gemmw<<<nblk, 512, 0, stream>>>(U, P2, U, 0, NNODES);

    // prop + bias + relu + final GEMV
    if (esrc_ws) {
        k_aggrf<<<NNODES / 4, 256, 0, stream>>>(U, rowptr, esrc, deg, b2, Wl, bl, out, NNODES);
    } else {
        k_aggr<0><<<NNODES / 4, 256, 0, stream>>>(U, rowptr, esrc, deg, nullptr, NNODES);
        k_final<<<NNODES / 4, 256, 0, stream>>>(U, b2, Wl, bl, out, NNODES);
    }
}